// Round 8
// baseline (4763.940 us; speedup 1.0000x reference)
//
#include <hip/hip_runtime.h>
#include <stdint.h>

// BiLSTM-CRF on gfx950 — fp32 (validated absmax 0.0). R14 = R13 refined.
// R13 proved: 512 thr + waves_per_eu(2,2) + asm-pinned weights -> real
// residency (VGPR+AGPR unified file), 1551 us (6.06 us/step), stream at
// 92 GB/s/CU (latency-limited, below the ~135 wall). R14 cuts the remaining
// overhead: (1) gate-pair split INSIDE the wave (lanes 0-31 = i,f; 32-63 =
// g,o of same 32 units) -> exchange via one __shfl, 1 barrier/step instead
// of 2, no LDS exch; (2) QR2 22->24, QL2 8->9 -> streamed quads 34->31
// (508 KB/step, -9%). Same per-gate acc0/acc1 q-ascending FP chain ->
// bitwise-same h. Probe + verbatim-R8 lo fallback retained.

#define T_ 256
#define B_ 64
#define EPAD 304
#define KTAG 20
#define TB_ (T_ * B_)

// hi partition (global k-quads 0..63, q ascending)
#define QR2 24                  // quads resident per gate-row (192 pinned)
#define QL2 9                   // quads in LDS per gate-row (144 KiB total)
#define QS2 31                  // quads streamed per gate-row

// lo (R8) partition
#define KR_LO 64
#define KLQ_LO 3
#define NQS_LO 45
#define WLDS_OFF_LO (2 * KR_LO * 1024)                    // 131072 floats
#define WSTR_OFF_LO (WLDS_OFF_LO + 2 * KLQ_LO * 1024 * 4) // 155648 floats

__device__ __forceinline__ float rlane(float v, int l) {
  return __int_as_float(__builtin_amdgcn_readlane(__float_as_int(v), l));
}

// ---------------- prep ----------------

__global__ void prep_embed(const int* __restrict__ x, const float* __restrict__ emb,
                           float* __restrict__ xsA) {
  int r = blockIdx.x;
  int tok = x[r];
  const float* src = emb + (size_t)tok * 300;
  for (int e = threadIdx.x; e < EPAD; e += 64)
    xsA[(size_t)r * EPAD + e] = (e < 300) ? src[e] : 0.f;
}

__global__ void prep_b0t(const float* __restrict__ Wih0, float* __restrict__ B0t) {
  int idx = blockIdx.x * 256 + threadIdx.x;
  if (idx >= 2048 * EPAD) return;
  int n = idx / EPAD, k = idx % EPAD;
  B0t[idx] = (k < 300) ? Wih0[(size_t)n * 300 + k] : 0.f;
}

__global__ void prep_bot64(const float* __restrict__ Wout, float* __restrict__ Bot,
                           const float* __restrict__ bout, float* __restrict__ biaso) {
  int idx = blockIdx.x * 256 + threadIdx.x;   // 64*512
  int n = idx >> 9, k = idx & 511;
  Bot[idx] = (n < KTAG) ? Wout[(size_t)n * 512 + k] : 0.f;
  if (idx < 64) biaso[idx] = (idx < KTAG) ? bout[idx] : 0.f;
}

// hi layout: whhU[d][q=k/4][gate][j][e]  (quad-major; lane j reads 16B at j*16)
__global__ void prep_whh4(const float* __restrict__ Whh, float* __restrict__ whhU) {
  int idx = blockIdx.x * 256 + threadIdx.x;   // 524288
  int d = idx >> 18, rem = idx & 262143, row = rem >> 8, k = rem & 255;
  float v = Whh[(size_t)d * 262144 + (size_t)row * 256 + k];
  int gt = row >> 8, j = row & 255;
  int q = k >> 2, e = k & 3;
  whhU[((((size_t)d * 64 + q) * 4 + gt) * 256 + j) * 4 + e] = v;
}

// lo layout (R8): thread tg owns row (tg&3)*256 + (tg>>2)
__global__ void prep_whh2(const float* __restrict__ Whh, float* __restrict__ whhL) {
  int idx = blockIdx.x * 256 + threadIdx.x;   // 524288
  int d = idx >> 18, rem = idx & 262143, k = rem >> 10, tg = rem & 1023;
  int row = (tg & 3) * 256 + (tg >> 2);
  float v = Whh[(size_t)d * 262144 + (size_t)row * 256 + k];
  if (k < KR_LO) {
    whhL[(size_t)(d * KR_LO + k) * 1024 + tg] = v;
  } else if (k < KR_LO + 12) {
    int kk = k - KR_LO, q = kk >> 2, e = kk & 3;
    whhL[WLDS_OFF_LO + (size_t)((d * KLQ_LO + q) * 1024 + tg) * 4 + e] = v;
  } else {
    int kk = k - KR_LO - 12, q = kk >> 2, e = kk & 3;
    whhL[WSTR_OFF_LO + (size_t)((d * NQS_LO + q) * 1024 + tg) * 4 + e] = v;
  }
}

// ---------------- fp32 GEMM: C[M,N] = A[M,K] * Bt[N,K]^T + bias ----------------
__global__ __launch_bounds__(256) void gemm_f32(
    const float* __restrict__ A, int lda, const float* __restrict__ Bt, int ldb,
    float* __restrict__ C, int ldc, const float* __restrict__ bias,
    int ntn, int K) {
  const int tm = blockIdx.x / ntn, tn = blockIdx.x % ntn;
  const int m0 = tm * 64, n0 = tn * 64;
  __shared__ __align__(16) float As[16][64];
  __shared__ __align__(16) float Bs[16][64];
  const int tid = threadIdx.x;
  const int mm = tid >> 2, kq = (tid & 3) * 4;
  const int tx = tid & 15, ty = tid >> 4;
  float acc[4][4] = {};
  for (int k0 = 0; k0 < K; k0 += 16) {
    float4 av = *(const float4*)&A[(size_t)(m0 + mm) * lda + k0 + kq];
    float4 bv = *(const float4*)&Bt[(size_t)(n0 + mm) * ldb + k0 + kq];
    __syncthreads();                       // guard prev-iter LDS reads
    As[kq + 0][mm] = av.x; As[kq + 1][mm] = av.y;
    As[kq + 2][mm] = av.z; As[kq + 3][mm] = av.w;
    Bs[kq + 0][mm] = bv.x; Bs[kq + 1][mm] = bv.y;
    Bs[kq + 2][mm] = bv.z; Bs[kq + 3][mm] = bv.w;
    __syncthreads();
#pragma unroll
    for (int kk = 0; kk < 16; ++kk) {
      float4 a4 = *(const float4*)&As[kk][ty * 4];
      float4 b4 = *(const float4*)&Bs[kk][tx * 4];
      acc[0][0] += a4.x * b4.x; acc[0][1] += a4.x * b4.y;
      acc[0][2] += a4.x * b4.z; acc[0][3] += a4.x * b4.w;
      acc[1][0] += a4.y * b4.x; acc[1][1] += a4.y * b4.y;
      acc[1][2] += a4.y * b4.z; acc[1][3] += a4.y * b4.w;
      acc[2][0] += a4.z * b4.x; acc[2][1] += a4.z * b4.y;
      acc[2][2] += a4.z * b4.z; acc[2][3] += a4.z * b4.w;
      acc[3][0] += a4.w * b4.x; acc[3][1] += a4.w * b4.y;
      acc[3][2] += a4.w * b4.z; acc[3][3] += a4.w * b4.w;
    }
  }
#pragma unroll
  for (int i = 0; i < 4; ++i)
#pragma unroll
    for (int j = 0; j < 4; ++j)
      C[(size_t)(m0 + ty * 4 + i) * ldc + n0 + tx * 4 + j] =
          acc[i][j] + bias[n0 + tx * 4 + j];
}

// ---------------- hi3 LSTM: 512 thr; wave-internal gate-pair split ----------
// Wave w, lane l: gp = l>>5 (0: gates i,f ; 1: gates g,o), unit jj =
// w*32 + (l&31). Exchange g,o -> i,f partner via one __shfl (no barrier).
// One barrier/step (hsd parity swap). Weights: 24 quads pinned VGPR/AGPR,
// 9 quads LDS (144 KiB), 31 streamed from L2.
__global__ __attribute__((amdgpu_flat_work_group_size(512, 512),
                          amdgpu_waves_per_eu(2, 2)))
void lstm_rec_hi3(const float* __restrict__ xg, const float* __restrict__ whhU,
                  float* __restrict__ out, const int* __restrict__ lens) {
  const int wg = blockIdx.x, d = wg & 1, b = wg >> 1;
  const int len = lens[b];
  const int tg = threadIdx.x;
  const int w = tg >> 6, l = tg & 63;
  const int lhalf = l & 31, gp = l >> 5;
  const int jj = w * 32 + lhalf;           // unit 0..255
  const int g0 = gp * 2;
  const float* wb = whhU + (size_t)d * 64 * 4096;  // ((q*4+g)*256 + j)*4 floats

  // resident quads 0..QR2-1 for both gate-rows (192 values), pinned
  float4 wA[QR2], wB[QR2];
#pragma unroll
  for (int q = 0; q < QR2; ++q) {
    wA[q] = *(const float4*)(wb + ((size_t)(q * 4 + g0) * 256 + jj) * 4);
    wB[q] = *(const float4*)(wb + ((size_t)(q * 4 + g0 + 1) * 256 + jj) * 4);
  }
#pragma unroll
  for (int q = 0; q < QR2; ++q) {
    asm volatile("" : "+v"(wA[q].x), "+v"(wA[q].y), "+v"(wA[q].z), "+v"(wA[q].w));
    asm volatile("" : "+v"(wB[q].x), "+v"(wB[q].y), "+v"(wB[q].z), "+v"(wB[q].w));
  }

  __shared__ __align__(16) float4 wlds[QL2][4][256];  // 144 KiB, quads QR2..QR2+8
  __shared__ __align__(16) float hsd[2][256];
  for (int i = tg; i < QL2 * 4 * 256; i += 512) {
    int q3 = i >> 10, g = (i >> 8) & 3, jx = i & 255;
    wlds[q3][g][jx] =
        *(const float4*)(wb + ((size_t)((QR2 + q3) * 4 + g) * 256 + jx) * 4);
  }
  if (tg < 256) hsd[0][tg] = 0.f;
  float c = 0.f;
  __syncthreads();

  for (int s = 0; s < len; ++s) {
    const int t = d ? (len - 1 - s) : s;   // bwd consumes & writes reversed pos
    const int rp = t * B_ + b;
    const size_t xb = (size_t)rp * 2048 + d * 1024 + (size_t)g0 * 256 + jj;
    float xv0 = xg[xb];                    // gate g0 row
    float xv1 = xg[xb + 256];              // gate g0+1 row
    float4 hv = *(const float4*)&hsd[s & 1][l * 4];  // lane l: h[4l..4l+3]

    float aA0 = 0.f, aA1 = 0.f, aB0 = 0.f, aB1 = 0.f;
    // resident quads (q 0..QR2-1), k ascending = validated FP chain
#pragma unroll
    for (int q = 0; q < QR2; ++q) {
      float b0 = rlane(hv.x, q), b1 = rlane(hv.y, q);
      float b2 = rlane(hv.z, q), b3 = rlane(hv.w, q);
      aA0 += wA[q].x * b0 + wA[q].y * b1;  aA1 += wA[q].z * b2 + wA[q].w * b3;
      aB0 += wB[q].x * b0 + wB[q].y * b1;  aB1 += wB[q].z * b2 + wB[q].w * b3;
    }
    // LDS quads (q QR2..QR2+QL2-1)
#pragma unroll
    for (int q3 = 0; q3 < QL2; ++q3) {
      int q = QR2 + q3;
      float b0 = rlane(hv.x, q), b1 = rlane(hv.y, q);
      float b2 = rlane(hv.z, q), b3 = rlane(hv.w, q);
      float4 wa = wlds[q3][g0][jj], wbq = wlds[q3][g0 + 1][jj];
      aA0 += wa.x * b0 + wa.y * b1;   aA1 += wa.z * b2 + wa.w * b3;
      aB0 += wbq.x * b0 + wbq.y * b1; aB1 += wbq.z * b2 + wbq.w * b3;
    }
    // streamed quads (q QR2+QL2..63) from L2
#pragma unroll 2
    for (int qs = 0; qs < QS2; ++qs) {
      int q = QR2 + QL2 + qs;
      float4 wa = *(const float4*)(wb + ((size_t)(q * 4 + g0) * 256 + jj) * 4);
      float4 wbq = *(const float4*)(wb + ((size_t)(q * 4 + g0 + 1) * 256 + jj) * 4);
      float b0 = rlane(hv.x, q), b1 = rlane(hv.y, q);
      float b2 = rlane(hv.z, q), b3 = rlane(hv.w, q);
      aA0 += wa.x * b0 + wa.y * b1;   aA1 += wa.z * b2 + wa.w * b3;
      aB0 += wbq.x * b0 + wbq.y * b1; aB1 += wbq.z * b2 + wbq.w * b3;
    }

    float aA = aA0 + aA1 + xv0;            // gp0: i ; gp1: g
    float aB = aB0 + aB1 + xv1;            // gp0: f ; gp1: o
    // pull partner's (g,o) from lanes 32-63 — wave-internal, no barrier
    float gG = __shfl(aA, lhalf + 32);
    float gO = __shfl(aB, lhalf + 32);
    if (gp == 0) {
      float si = 1.f / (1.f + expf(-aA));  // i
      float sf = 1.f / (1.f + expf(-aB));  // f
      float so = 1.f / (1.f + expf(-gO));  // o
      c = sf * c + si * tanhf(gG);         // g
      float h = so * tanhf(c);
      hsd[(s + 1) & 1][jj] = h;
      out[(size_t)rp * 512 + d * 256 + jj] = h;
    }
    __syncthreads();                        // h_s+1 visible to all waves
  }
  if (gp == 0)                              // pack_padded: padded outputs zero
    for (int t = len; t < T_; ++t)
      out[(size_t)(t * B_ + b) * 512 + d * 256 + jj] = 0.f;
}

// ---------------- lo LSTM: verbatim R8 (proven 1963 us, absmax 0.0) ----------
__global__ __launch_bounds__(1024, 4) void lstm_rec_lo(
    const float* __restrict__ xg, const float* __restrict__ whhL,
    float* __restrict__ out, const int* __restrict__ lens) {
  const int wg = blockIdx.x, dir = wg & 1, b = wg >> 1;
  const int len = lens[b];
  const int tg = threadIdx.x;
  const int j = tg >> 2, gt = tg & 3;
  const int row = gt * 256 + j;

  float wres[KR_LO];
#pragma unroll
  for (int k = 0; k < KR_LO; ++k)
    wres[k] = whhL[(size_t)(dir * KR_LO + k) * 1024 + tg];

  __shared__ __align__(16) float4 wlds[KLQ_LO][1024];
  __shared__ __align__(16) float hsd[2][256];
#pragma unroll
  for (int q = 0; q < KLQ_LO; ++q)
    wlds[q][tg] = *(const float4*)&whhL[WLDS_OFF_LO + (size_t)((dir * KLQ_LO + q) * 1024 + tg) * 4];
  if (tg < 256) hsd[0][tg] = 0.f;
  float c = 0.f;
  __syncthreads();

  const float* sp = whhL + WSTR_OFF_LO + (size_t)dir * NQS_LO * 4096 + (size_t)tg * 4;
  const int lane = tg & 63, qb = lane & ~3;

  for (int s = 0; s < len; ++s) {
    const int t = dir ? (len - 1 - s) : s;
    const int rp = t * B_ + b;
    float xv = xg[(size_t)rp * 2048 + dir * 1024 + row];
    float4 hv = *(const float4*)&hsd[s & 1][lane * 4];

    float acc0 = 0.f, acc1 = 0.f;
#pragma unroll
    for (int q = 0; q < KR_LO / 4; ++q) {
      float b0 = rlane(hv.x, q), b1 = rlane(hv.y, q);
      float b2 = rlane(hv.z, q), b3 = rlane(hv.w, q);
      acc0 += wres[4 * q + 0] * b0 + wres[4 * q + 1] * b1;
      acc1 += wres[4 * q + 2] * b2 + wres[4 * q + 3] * b3;
    }
#pragma unroll
    for (int q3 = 0; q3 < KLQ_LO; ++q3) {
      int q = KR_LO / 4 + q3;
      float4 wl = wlds[q3][tg];
      float b0 = rlane(hv.x, q), b1 = rlane(hv.y, q);
      float b2 = rlane(hv.z, q), b3 = rlane(hv.w, q);
      acc0 += wl.x * b0 + wl.y * b1;
      acc1 += wl.z * b2 + wl.w * b3;
    }
#pragma unroll 5
    for (int qq = 0; qq < NQS_LO; ++qq) {
      int q = KR_LO / 4 + KLQ_LO + qq;
      float4 wv = *(const float4*)(sp + (size_t)qq * 4096);
      float b0 = rlane(hv.x, q), b1 = rlane(hv.y, q);
      float b2 = rlane(hv.z, q), b3 = rlane(hv.w, q);
      acc0 += wv.x * b0 + wv.y * b1;
      acc1 += wv.z * b2 + wv.w * b3;
    }

    float a = acc0 + acc1 + xv;
    float v1 = __shfl(a, qb | 1);
    float v2 = __shfl(a, qb | 2);
    float v3 = __shfl(a, qb | 3);
    if (gt == 0) {
      float si = 1.f / (1.f + expf(-a));
      float sf = 1.f / (1.f + expf(-v1));
      float so = 1.f / (1.f + expf(-v3));
      c = sf * c + si * tanhf(v2);
      float h = so * tanhf(c);
      hsd[(s + 1) & 1][j] = h;
      out[(size_t)rp * 512 + dir * 256 + j] = h;
    }
    __syncthreads();
  }
  for (int t = len; t < T_; ++t)
    if (gt == 0) out[(size_t)(t * B_ + b) * 512 + dir * 256 + j] = 0.f;
}

// ---------------- Viterbi (one wave per batch; ref fp-op order) ----------------
__global__ __launch_bounds__(64) void viterbi(
    const float* __restrict__ emis, const float* __restrict__ trans,
    const float* __restrict__ startv, const float* __restrict__ endv,
    const int* __restrict__ lens, int* __restrict__ outp) {
  int b = blockIdx.x, lane = threadIdx.x;
  __shared__ float tr[KTAG * KTAG];
  __shared__ float fin[KTAG];
  __shared__ unsigned char hist[T_ * KTAG];
  for (int i = lane; i < KTAG * KTAG; i += 64) tr[i] = trans[i];
  int len = lens[b];
  float score = (lane < KTAG) ? startv[lane] + emis[(size_t)b * 64 + lane] : -3e38f;
  __syncthreads();
  for (int t = 1; t < len; ++t) {
    float e = (lane < KTAG) ? emis[(size_t)(t * B_ + b) * 64 + lane] : 0.f;
    float best = -3e38f; int bp = 0;
    for (int p = 0; p < KTAG; ++p) {         // ascending p + strict '>': first-index
      float cand = (__shfl(score, p) + tr[p * KTAG + lane]) + e;  // ref op order
      if (cand > best) { best = cand; bp = p; }
    }
    if (lane < KTAG) { score = best; hist[t * KTAG + lane] = (unsigned char)bp; }
  }
  if (lane < KTAG) fin[lane] = score + endv[lane];
  __syncthreads();
  if (lane == 0) {
    float bb = -3e38f; int tag = 0;
    for (int p = 0; p < KTAG; ++p)
      if (fin[p] > bb) { bb = fin[p]; tag = p; }
    for (int t = len - 1; t >= 1; --t) {
      outp[t * B_ + b] = tag;
      tag = hist[t * KTAG + tag];
    }
    outp[b] = tag;
  }
  for (int t = len + lane; t < T_; t += 64) outp[t * B_ + b] = 0;
}

// ---------------- diagnostics (slim) ----------------
__global__ void sentinel_fill(int* __restrict__ outp, int val) {
  int i = blockIdx.x * 256 + threadIdx.x;
  if (i < TB_) outp[i] = val;
}
__global__ void diag_init(int* __restrict__ f) { if (threadIdx.x == 0) f[0] = 0; }
__global__ void check_nan(const float* __restrict__ p, long n, int* __restrict__ f) {
  long i0 = (long)blockIdx.x * 256 + threadIdx.x;
  int bad = 0;
  for (long i = i0; i < n; i += (long)gridDim.x * 256)
    if (!(fabsf(p[i]) <= 1e8f)) bad = 1;
  if (bad) atomicOr(&f[0], 1);
}
__global__ void verdict(const int* __restrict__ f, int* __restrict__ outp) {
  if (f[0]) outp[threadIdx.x] = -4096;
}

// ---------------- host ----------------

extern "C" void kernel_launch(void* const* d_in, const int* in_sizes, int n_in,
                              void* d_out, int out_size, void* d_ws, size_t ws_size,
                              hipStream_t stream) {
  int* outp = (int*)d_out;

  static const int exp_sizes[14] = {16384, 64, 15000000, 614400, 524288, 2048,
                                    1048576, 524288, 2048, 10240, 20, 400, 20, 20};
  int badi = (n_in == 14) ? -1 : 14;
  if (badi < 0)
    for (int i = 0; i < 14; ++i)
      if (in_sizes[i] != exp_sizes[i]) { badi = i; break; }
  if (badi >= 0) {
    hipLaunchKernelGGL(sentinel_fill, dim3((TB_ + 255) / 256), dim3(256), 0, stream,
                       outp, -(20000 + badi));
    return;
  }

  const int*   x      = (const int*)d_in[0];
  const int*   lens   = (const int*)d_in[1];
  const float* emb    = (const float*)d_in[2];
  const float* Wih0   = (const float*)d_in[3];
  const float* Whh0   = (const float*)d_in[4];
  const float* b0     = (const float*)d_in[5];
  const float* Wih1   = (const float*)d_in[6];
  const float* Whh1   = (const float*)d_in[7];
  const float* b1     = (const float*)d_in[8];
  const float* Wout   = (const float*)d_in[9];
  const float* bout   = (const float*)d_in[10];
  const float* trans  = (const float*)d_in[11];
  const float* startv = (const float*)d_in[12];
  const float* endv   = (const float*)d_in[13];

  // pick hi3 only if the allocator provably granted residency (no scratch);
  // else lo (verbatim R8 floor).
  static int chosen = -1;
  if (chosen < 0) {
    chosen = 0;
    hipFuncAttributes fa;
    if (hipFuncGetAttributes(&fa, reinterpret_cast<const void*>(&lstm_rec_hi3)) ==
            hipSuccess &&
        fa.localSizeBytes == 0 && fa.numRegs >= 160)
      chosen = 1;
  }

  const size_t sz_whh = (size_t)524288 * 4;   // 2 MiB per layer per layout

  const size_t need =
      (size_t)TB_ * 2048 * 4      // xg
    + (size_t)TB_ * EPAD * 4     // xsA
    + (size_t)TB_ * 512 * 4      // outh
    + (size_t)2048 * EPAD * 4    // B0t
    + (size_t)64 * 512 * 4       // Bot
    + 4 * sz_whh                 // whh{0,1} x {U,L}
    + 64 * 4                     // biaso
    + (size_t)TB_ * 64 * 4       // emis
    + 64;                        // diag

  if (ws_size < need) {
    hipLaunchKernelGGL(sentinel_fill, dim3((TB_ + 255) / 256), dim3(256), 0, stream,
                       outp, -(int)(10000 + (ws_size >> 20)));
    return;
  }

  char* w = (char*)d_ws;
  float* xg    = (float*)w;  w += (size_t)TB_ * 2048 * 4;
  float* xsA   = (float*)w;  w += (size_t)TB_ * EPAD * 4;
  float* outh  = (float*)w;  w += (size_t)TB_ * 512 * 4;
  float* B0t   = (float*)w;  w += (size_t)2048 * EPAD * 4;
  float* Bot   = (float*)w;  w += (size_t)64 * 512 * 4;
  float* whh0U = (float*)w;  w += sz_whh;
  float* whh1U = (float*)w;  w += sz_whh;
  float* whh0L = (float*)w;  w += sz_whh;
  float* whh1L = (float*)w;  w += sz_whh;
  float* biaso = (float*)w;  w += 64 * 4;
  float* emis  = (float*)w;  w += (size_t)TB_ * 64 * 4;
  int*   diag  = (int*)w;    w += 64;

  hipLaunchKernelGGL(diag_init, dim3(1), dim3(64), 0, stream, diag);
  hipLaunchKernelGGL(prep_embed, dim3(TB_), dim3(64), 0, stream, x, emb, xsA);
  hipLaunchKernelGGL(prep_b0t, dim3((2048 * EPAD + 255) / 256), dim3(256), 0, stream, Wih0, B0t);
  hipLaunchKernelGGL(prep_bot64, dim3(128), dim3(256), 0, stream, Wout, Bot, bout, biaso);
  if (chosen == 1) {
    hipLaunchKernelGGL(prep_whh4, dim3(2048), dim3(256), 0, stream, Whh0, whh0U);
    hipLaunchKernelGGL(prep_whh4, dim3(2048), dim3(256), 0, stream, Whh1, whh1U);
  } else {
    hipLaunchKernelGGL(prep_whh2, dim3(2048), dim3(256), 0, stream, Whh0, whh0L);
    hipLaunchKernelGGL(prep_whh2, dim3(2048), dim3(256), 0, stream, Whh1, whh1L);
  }

  // layer 0
  hipLaunchKernelGGL(gemm_f32, dim3(256 * 32), dim3(256), 0, stream,
                     xsA, EPAD, B0t, EPAD, xg, 2048, b0, 32, EPAD);
  if (chosen == 1)
    hipLaunchKernelGGL(lstm_rec_hi3, dim3(128), dim3(512), 0, stream, xg, whh0U, outh, lens);
  else
    hipLaunchKernelGGL(lstm_rec_lo, dim3(128), dim3(1024), 0, stream, xg, whh0L, outh, lens);
  // layer 1 (Wih1/b1 used directly: [2048][512] row-major, K=512)
  hipLaunchKernelGGL(gemm_f32, dim3(256 * 32), dim3(256), 0, stream,
                     outh, 512, Wih1, 512, xg, 2048, b1, 32, 512);
  if (chosen == 1)
    hipLaunchKernelGGL(lstm_rec_hi3, dim3(128), dim3(512), 0, stream, xg, whh1U, outh, lens);
  else
    hipLaunchKernelGGL(lstm_rec_lo, dim3(128), dim3(1024), 0, stream, xg, whh1L, outh, lens);
  // emissions (N padded to 64) + decode
  hipLaunchKernelGGL(gemm_f32, dim3(256), dim3(256), 0, stream,
                     outh, 512, Bot, 512, emis, 64, biaso, 1, 512);
  hipLaunchKernelGGL(check_nan, dim3(256), dim3(256), 0, stream,
                     emis, (long)TB_ * 64, diag);
  hipLaunchKernelGGL(viterbi, dim3(B_), dim3(64), 0, stream,
                     emis, trans, startv, endv, lens, outp);
  hipLaunchKernelGGL(verdict, dim3(1), dim3(64), 0, stream, diag, outp);
}

// Round 9
// 4000.925 us; speedup vs baseline: 1.1907x; 1.1907x over previous
//
#include <hip/hip_runtime.h>
#include <stdint.h>

// BiLSTM-CRF on gfx950 — fp32 (validated absmax 0.0). R15: probe-gated
// cascade hi3b -> hi2 -> lo. R14's hi3 failed its probe because QR2 24 (192
// pinned) overran the 256-reg budget -> scratch -> rejected -> lo ran (4764).
// hi3b keeps R13's PROVEN register footprint (QR2=22 / 176 pinned; QL2=9 is
// LDS-only) and adds only the register-neutral change: gate-pair split inside
// the wave (lanes 0-31 = i,f; lanes 32-63 = g,o of the same 32 units), so the
// gate exchange is one __shfl and there is 1 barrier/step instead of 2.
// hi2 = R13 verbatim (1551 us). lo = R8 verbatim (1963 us).

#define T_ 256
#define B_ 64
#define EPAD 304
#define KTAG 20
#define TB_ (T_ * B_)

// hi partitions (global k-quads 0..63, q ascending)
#define QR2 22                  // quads resident per gate-row (176 pinned, proven)
#define QL2A 8                  // hi2: quads in LDS (128 KiB)
#define QS2A 34                 // hi2: streamed
#define QL2B 9                  // hi3b: quads in LDS (144 KiB)
#define QS2B 33                 // hi3b: streamed

// lo (R8) partition
#define KR_LO 64
#define KLQ_LO 3
#define NQS_LO 45
#define WLDS_OFF_LO (2 * KR_LO * 1024)                    // 131072 floats
#define WSTR_OFF_LO (WLDS_OFF_LO + 2 * KLQ_LO * 1024 * 4) // 155648 floats

__device__ __forceinline__ float rlane(float v, int l) {
  return __int_as_float(__builtin_amdgcn_readlane(__float_as_int(v), l));
}

// ---------------- prep ----------------

__global__ void prep_embed(const int* __restrict__ x, const float* __restrict__ emb,
                           float* __restrict__ xsA) {
  int r = blockIdx.x;
  int tok = x[r];
  const float* src = emb + (size_t)tok * 300;
  for (int e = threadIdx.x; e < EPAD; e += 64)
    xsA[(size_t)r * EPAD + e] = (e < 300) ? src[e] : 0.f;
}

__global__ void prep_b0t(const float* __restrict__ Wih0, float* __restrict__ B0t) {
  int idx = blockIdx.x * 256 + threadIdx.x;
  if (idx >= 2048 * EPAD) return;
  int n = idx / EPAD, k = idx % EPAD;
  B0t[idx] = (k < 300) ? Wih0[(size_t)n * 300 + k] : 0.f;
}

__global__ void prep_bot64(const float* __restrict__ Wout, float* __restrict__ Bot,
                           const float* __restrict__ bout, float* __restrict__ biaso) {
  int idx = blockIdx.x * 256 + threadIdx.x;   // 64*512
  int n = idx >> 9, k = idx & 511;
  Bot[idx] = (n < KTAG) ? Wout[(size_t)n * 512 + k] : 0.f;
  if (idx < 64) biaso[idx] = (idx < KTAG) ? bout[idx] : 0.f;
}

// hi layout: whhU[d][q=k/4][gate][j][e]  (quad-major; lane j reads 16B at j*16)
__global__ void prep_whh4(const float* __restrict__ Whh, float* __restrict__ whhU) {
  int idx = blockIdx.x * 256 + threadIdx.x;   // 524288
  int d = idx >> 18, rem = idx & 262143, row = rem >> 8, k = rem & 255;
  float v = Whh[(size_t)d * 262144 + (size_t)row * 256 + k];
  int gt = row >> 8, j = row & 255;
  int q = k >> 2, e = k & 3;
  whhU[((((size_t)d * 64 + q) * 4 + gt) * 256 + j) * 4 + e] = v;
}

// lo layout (R8): thread tg owns row (tg&3)*256 + (tg>>2)
__global__ void prep_whh2(const float* __restrict__ Whh, float* __restrict__ whhL) {
  int idx = blockIdx.x * 256 + threadIdx.x;   // 524288
  int d = idx >> 18, rem = idx & 262143, k = rem >> 10, tg = rem & 1023;
  int row = (tg & 3) * 256 + (tg >> 2);
  float v = Whh[(size_t)d * 262144 + (size_t)row * 256 + k];
  if (k < KR_LO) {
    whhL[(size_t)(d * KR_LO + k) * 1024 + tg] = v;
  } else if (k < KR_LO + 12) {
    int kk = k - KR_LO, q = kk >> 2, e = kk & 3;
    whhL[WLDS_OFF_LO + (size_t)((d * KLQ_LO + q) * 1024 + tg) * 4 + e] = v;
  } else {
    int kk = k - KR_LO - 12, q = kk >> 2, e = kk & 3;
    whhL[WSTR_OFF_LO + (size_t)((d * NQS_LO + q) * 1024 + tg) * 4 + e] = v;
  }
}

// ---------------- fp32 GEMM: C[M,N] = A[M,K] * Bt[N,K]^T + bias ----------------
__global__ __launch_bounds__(256) void gemm_f32(
    const float* __restrict__ A, int lda, const float* __restrict__ Bt, int ldb,
    float* __restrict__ C, int ldc, const float* __restrict__ bias,
    int ntn, int K) {
  const int tm = blockIdx.x / ntn, tn = blockIdx.x % ntn;
  const int m0 = tm * 64, n0 = tn * 64;
  __shared__ __align__(16) float As[16][64];
  __shared__ __align__(16) float Bs[16][64];
  const int tid = threadIdx.x;
  const int mm = tid >> 2, kq = (tid & 3) * 4;
  const int tx = tid & 15, ty = tid >> 4;
  float acc[4][4] = {};
  for (int k0 = 0; k0 < K; k0 += 16) {
    float4 av = *(const float4*)&A[(size_t)(m0 + mm) * lda + k0 + kq];
    float4 bv = *(const float4*)&Bt[(size_t)(n0 + mm) * ldb + k0 + kq];
    __syncthreads();                       // guard prev-iter LDS reads
    As[kq + 0][mm] = av.x; As[kq + 1][mm] = av.y;
    As[kq + 2][mm] = av.z; As[kq + 3][mm] = av.w;
    Bs[kq + 0][mm] = bv.x; Bs[kq + 1][mm] = bv.y;
    Bs[kq + 2][mm] = bv.z; Bs[kq + 3][mm] = bv.w;
    __syncthreads();
#pragma unroll
    for (int kk = 0; kk < 16; ++kk) {
      float4 a4 = *(const float4*)&As[kk][ty * 4];
      float4 b4 = *(const float4*)&Bs[kk][tx * 4];
      acc[0][0] += a4.x * b4.x; acc[0][1] += a4.x * b4.y;
      acc[0][2] += a4.x * b4.z; acc[0][3] += a4.x * b4.w;
      acc[1][0] += a4.y * b4.x; acc[1][1] += a4.y * b4.y;
      acc[1][2] += a4.y * b4.z; acc[1][3] += a4.y * b4.w;
      acc[2][0] += a4.z * b4.x; acc[2][1] += a4.z * b4.y;
      acc[2][2] += a4.z * b4.z; acc[2][3] += a4.z * b4.w;
      acc[3][0] += a4.w * b4.x; acc[3][1] += a4.w * b4.y;
      acc[3][2] += a4.w * b4.z; acc[3][3] += a4.w * b4.w;
    }
  }
#pragma unroll
  for (int i = 0; i < 4; ++i)
#pragma unroll
    for (int j = 0; j < 4; ++j)
      C[(size_t)(m0 + ty * 4 + i) * ldc + n0 + tx * 4 + j] =
          acc[i][j] + bias[n0 + tx * 4 + j];
}

// ---------------- hi3b LSTM: wave-internal gate-pair split ----------
// Wave w, lane l: gp = l>>5 (0: gates i,f ; 1: g,o), unit jj = w*32+(l&31).
// Exchange via one __shfl; ONE barrier/step. QR2=22 pinned (R13-proven
// footprint), QL2B=9 LDS quads (144 KiB), QS2B=33 streamed.
__global__ __attribute__((amdgpu_flat_work_group_size(512, 512),
                          amdgpu_waves_per_eu(2, 2)))
void lstm_rec_hi3b(const float* __restrict__ xg, const float* __restrict__ whhU,
                   float* __restrict__ out, const int* __restrict__ lens) {
  const int wg = blockIdx.x, d = wg & 1, b = wg >> 1;
  const int len = lens[b];
  const int tg = threadIdx.x;
  const int w = tg >> 6, l = tg & 63;
  const int lhalf = l & 31, gp = l >> 5;
  const int jj = w * 32 + lhalf;           // unit 0..255
  const int g0 = gp * 2;
  const float* wb = whhU + (size_t)d * 64 * 4096;

  float4 wA[QR2], wB[QR2];
#pragma unroll
  for (int q = 0; q < QR2; ++q) {
    wA[q] = *(const float4*)(wb + ((size_t)(q * 4 + g0) * 256 + jj) * 4);
    wB[q] = *(const float4*)(wb + ((size_t)(q * 4 + g0 + 1) * 256 + jj) * 4);
  }
#pragma unroll
  for (int q = 0; q < QR2; ++q) {
    asm volatile("" : "+v"(wA[q].x), "+v"(wA[q].y), "+v"(wA[q].z), "+v"(wA[q].w));
    asm volatile("" : "+v"(wB[q].x), "+v"(wB[q].y), "+v"(wB[q].z), "+v"(wB[q].w));
  }

  __shared__ __align__(16) float4 wlds[QL2B][4][256];  // 144 KiB
  __shared__ __align__(16) float hsd[2][256];
  for (int i = tg; i < QL2B * 4 * 256; i += 512) {
    int q3 = i >> 10, g = (i >> 8) & 3, jx = i & 255;
    wlds[q3][g][jx] =
        *(const float4*)(wb + ((size_t)((QR2 + q3) * 4 + g) * 256 + jx) * 4);
  }
  if (tg < 256) hsd[0][tg] = 0.f;
  float c = 0.f;
  __syncthreads();

  for (int s = 0; s < len; ++s) {
    const int t = d ? (len - 1 - s) : s;   // bwd consumes & writes reversed pos
    const int rp = t * B_ + b;
    const size_t xb = (size_t)rp * 2048 + d * 1024 + (size_t)g0 * 256 + jj;
    float xv0 = xg[xb];                    // gate g0 row
    float xv1 = xg[xb + 256];              // gate g0+1 row
    float4 hv = *(const float4*)&hsd[s & 1][l * 4];  // lane l: h[4l..4l+3]

    float aA0 = 0.f, aA1 = 0.f, aB0 = 0.f, aB1 = 0.f;
#pragma unroll
    for (int q = 0; q < QR2; ++q) {        // k ascending = validated FP chain
      float b0 = rlane(hv.x, q), b1 = rlane(hv.y, q);
      float b2 = rlane(hv.z, q), b3 = rlane(hv.w, q);
      aA0 += wA[q].x * b0 + wA[q].y * b1;  aA1 += wA[q].z * b2 + wA[q].w * b3;
      aB0 += wB[q].x * b0 + wB[q].y * b1;  aB1 += wB[q].z * b2 + wB[q].w * b3;
    }
#pragma unroll
    for (int q3 = 0; q3 < QL2B; ++q3) {
      int q = QR2 + q3;
      float b0 = rlane(hv.x, q), b1 = rlane(hv.y, q);
      float b2 = rlane(hv.z, q), b3 = rlane(hv.w, q);
      float4 wa = wlds[q3][g0][jj], wbq = wlds[q3][g0 + 1][jj];
      aA0 += wa.x * b0 + wa.y * b1;   aA1 += wa.z * b2 + wa.w * b3;
      aB0 += wbq.x * b0 + wbq.y * b1; aB1 += wbq.z * b2 + wbq.w * b3;
    }
#pragma unroll 2
    for (int qs = 0; qs < QS2B; ++qs) {
      int q = QR2 + QL2B + qs;
      float4 wa = *(const float4*)(wb + ((size_t)(q * 4 + g0) * 256 + jj) * 4);
      float4 wbq = *(const float4*)(wb + ((size_t)(q * 4 + g0 + 1) * 256 + jj) * 4);
      float b0 = rlane(hv.x, q), b1 = rlane(hv.y, q);
      float b2 = rlane(hv.z, q), b3 = rlane(hv.w, q);
      aA0 += wa.x * b0 + wa.y * b1;   aA1 += wa.z * b2 + wa.w * b3;
      aB0 += wbq.x * b0 + wbq.y * b1; aB1 += wbq.z * b2 + wbq.w * b3;
    }

    float aA = aA0 + aA1 + xv0;            // gp0: i ; gp1: g
    float aB = aB0 + aB1 + xv1;            // gp0: f ; gp1: o
    float gG = __shfl(aA, lhalf + 32);     // partner's g (wave-internal)
    float gO = __shfl(aB, lhalf + 32);     // partner's o
    if (gp == 0) {
      float si = 1.f / (1.f + expf(-aA));  // i
      float sf = 1.f / (1.f + expf(-aB));  // f
      float so = 1.f / (1.f + expf(-gO));  // o
      c = sf * c + si * tanhf(gG);         // g
      float h = so * tanhf(c);
      hsd[(s + 1) & 1][jj] = h;
      out[(size_t)rp * 512 + d * 256 + jj] = h;
    }
    __syncthreads();                        // one barrier/step
  }
  if (gp == 0)                              // pack_padded: padded outputs zero
    for (int t = len; t < T_; ++t)
      out[(size_t)(t * B_ + b) * 512 + d * 256 + jj] = 0.f;
}

// ---------------- hi2 LSTM: R13 verbatim (proven 1551 us) ----------
__global__ __attribute__((amdgpu_flat_work_group_size(512, 512),
                          amdgpu_waves_per_eu(2, 2)))
void lstm_rec_hi2(const float* __restrict__ xg, const float* __restrict__ whhU,
                  float* __restrict__ out, const int* __restrict__ lens) {
  const int wg = blockIdx.x, d = wg & 1, b = wg >> 1;
  const int len = lens[b];
  const int tg = threadIdx.x;
  const int j = tg & 255, gp = tg >> 8;    // gp 0: gates i,f ; gp 1: gates g,o
  const int g0 = gp * 2;
  const int l = tg & 63;
  const float* wb = whhU + (size_t)d * 64 * 4096;

  float4 wA[QR2], wB[QR2];
#pragma unroll
  for (int q = 0; q < QR2; ++q) {
    wA[q] = *(const float4*)(wb + ((size_t)(q * 4 + g0) * 256 + j) * 4);
    wB[q] = *(const float4*)(wb + ((size_t)(q * 4 + g0 + 1) * 256 + j) * 4);
  }
#pragma unroll
  for (int q = 0; q < QR2; ++q) {
    asm volatile("" : "+v"(wA[q].x), "+v"(wA[q].y), "+v"(wA[q].z), "+v"(wA[q].w));
    asm volatile("" : "+v"(wB[q].x), "+v"(wB[q].y), "+v"(wB[q].z), "+v"(wB[q].w));
  }

  __shared__ __align__(16) float4 wlds[QL2A][4][256];  // 128 KiB
  __shared__ __align__(16) float hsd[2][256];
  __shared__ __align__(8) float2 exch[256];
  for (int i = tg; i < QL2A * 4 * 256; i += 512) {
    int q3 = i >> 10, g = (i >> 8) & 3, jj = i & 255;
    wlds[q3][g][jj] =
        *(const float4*)(wb + ((size_t)((QR2 + q3) * 4 + g) * 256 + jj) * 4);
  }
  if (tg < 256) hsd[0][tg] = 0.f;
  float c = 0.f;
  __syncthreads();

  for (int s = 0; s < len; ++s) {
    const int t = d ? (len - 1 - s) : s;
    const int rp = t * B_ + b;
    const size_t xb = (size_t)rp * 2048 + d * 1024 + (size_t)g0 * 256 + j;
    float xv0 = xg[xb];
    float xv1 = xg[xb + 256];
    float4 hv = *(const float4*)&hsd[s & 1][l * 4];

    float aA0 = 0.f, aA1 = 0.f, aB0 = 0.f, aB1 = 0.f;
#pragma unroll
    for (int q = 0; q < QR2; ++q) {
      float b0 = rlane(hv.x, q), b1 = rlane(hv.y, q);
      float b2 = rlane(hv.z, q), b3 = rlane(hv.w, q);
      aA0 += wA[q].x * b0 + wA[q].y * b1;  aA1 += wA[q].z * b2 + wA[q].w * b3;
      aB0 += wB[q].x * b0 + wB[q].y * b1;  aB1 += wB[q].z * b2 + wB[q].w * b3;
    }
#pragma unroll
    for (int q3 = 0; q3 < QL2A; ++q3) {
      int q = QR2 + q3;
      float b0 = rlane(hv.x, q), b1 = rlane(hv.y, q);
      float b2 = rlane(hv.z, q), b3 = rlane(hv.w, q);
      float4 wa = wlds[q3][g0][j], wbq = wlds[q3][g0 + 1][j];
      aA0 += wa.x * b0 + wa.y * b1;   aA1 += wa.z * b2 + wa.w * b3;
      aB0 += wbq.x * b0 + wbq.y * b1; aB1 += wbq.z * b2 + wbq.w * b3;
    }
#pragma unroll 2
    for (int qs = 0; qs < QS2A; ++qs) {
      int q = QR2 + QL2A + qs;
      float4 wa = *(const float4*)(wb + ((size_t)(q * 4 + g0) * 256 + j) * 4);
      float4 wbq = *(const float4*)(wb + ((size_t)(q * 4 + g0 + 1) * 256 + j) * 4);
      float b0 = rlane(hv.x, q), b1 = rlane(hv.y, q);
      float b2 = rlane(hv.z, q), b3 = rlane(hv.w, q);
      aA0 += wa.x * b0 + wa.y * b1;   aA1 += wa.z * b2 + wa.w * b3;
      aB0 += wbq.x * b0 + wbq.y * b1; aB1 += wbq.z * b2 + wbq.w * b3;
    }

    float aA = aA0 + aA1 + xv0;
    float aB = aB0 + aB1 + xv1;
    if (gp == 1) exch[j] = make_float2(aA, aB);
    __syncthreads();
    if (gp == 0) {
      float2 go = exch[j];
      float si = 1.f / (1.f + expf(-aA));
      float sf = 1.f / (1.f + expf(-aB));
      float so = 1.f / (1.f + expf(-go.y));
      c = sf * c + si * tanhf(go.x);
      float h = so * tanhf(c);
      hsd[(s + 1) & 1][j] = h;
      out[(size_t)rp * 512 + d * 256 + j] = h;
    }
    __syncthreads();
  }
  if (gp == 0)
    for (int t = len; t < T_; ++t)
      out[(size_t)(t * B_ + b) * 512 + d * 256 + j] = 0.f;
}

// ---------------- lo LSTM: verbatim R8 (proven 1963 us, absmax 0.0) ----------
__global__ __launch_bounds__(1024, 4) void lstm_rec_lo(
    const float* __restrict__ xg, const float* __restrict__ whhL,
    float* __restrict__ out, const int* __restrict__ lens) {
  const int wg = blockIdx.x, dir = wg & 1, b = wg >> 1;
  const int len = lens[b];
  const int tg = threadIdx.x;
  const int j = tg >> 2, gt = tg & 3;
  const int row = gt * 256 + j;

  float wres[KR_LO];
#pragma unroll
  for (int k = 0; k < KR_LO; ++k)
    wres[k] = whhL[(size_t)(dir * KR_LO + k) * 1024 + tg];

  __shared__ __align__(16) float4 wlds[KLQ_LO][1024];
  __shared__ __align__(16) float hsd[2][256];
#pragma unroll
  for (int q = 0; q < KLQ_LO; ++q)
    wlds[q][tg] = *(const float4*)&whhL[WLDS_OFF_LO + (size_t)((dir * KLQ_LO + q) * 1024 + tg) * 4];
  if (tg < 256) hsd[0][tg] = 0.f;
  float c = 0.f;
  __syncthreads();

  const float* sp = whhL + WSTR_OFF_LO + (size_t)dir * NQS_LO * 4096 + (size_t)tg * 4;
  const int lane = tg & 63, qb = lane & ~3;

  for (int s = 0; s < len; ++s) {
    const int t = dir ? (len - 1 - s) : s;
    const int rp = t * B_ + b;
    float xv = xg[(size_t)rp * 2048 + dir * 1024 + row];
    float4 hv = *(const float4*)&hsd[s & 1][lane * 4];

    float acc0 = 0.f, acc1 = 0.f;
#pragma unroll
    for (int q = 0; q < KR_LO / 4; ++q) {
      float b0 = rlane(hv.x, q), b1 = rlane(hv.y, q);
      float b2 = rlane(hv.z, q), b3 = rlane(hv.w, q);
      acc0 += wres[4 * q + 0] * b0 + wres[4 * q + 1] * b1;
      acc1 += wres[4 * q + 2] * b2 + wres[4 * q + 3] * b3;
    }
#pragma unroll
    for (int q3 = 0; q3 < KLQ_LO; ++q3) {
      int q = KR_LO / 4 + q3;
      float4 wl = wlds[q3][tg];
      float b0 = rlane(hv.x, q), b1 = rlane(hv.y, q);
      float b2 = rlane(hv.z, q), b3 = rlane(hv.w, q);
      acc0 += wl.x * b0 + wl.y * b1;
      acc1 += wl.z * b2 + wl.w * b3;
    }
#pragma unroll 5
    for (int qq = 0; qq < NQS_LO; ++qq) {
      int q = KR_LO / 4 + KLQ_LO + qq;
      float4 wv = *(const float4*)(sp + (size_t)qq * 4096);
      float b0 = rlane(hv.x, q), b1 = rlane(hv.y, q);
      float b2 = rlane(hv.z, q), b3 = rlane(hv.w, q);
      acc0 += wv.x * b0 + wv.y * b1;
      acc1 += wv.z * b2 + wv.w * b3;
    }

    float a = acc0 + acc1 + xv;
    float v1 = __shfl(a, qb | 1);
    float v2 = __shfl(a, qb | 2);
    float v3 = __shfl(a, qb | 3);
    if (gt == 0) {
      float si = 1.f / (1.f + expf(-a));
      float sf = 1.f / (1.f + expf(-v1));
      float so = 1.f / (1.f + expf(-v3));
      c = sf * c + si * tanhf(v2);
      float h = so * tanhf(c);
      hsd[(s + 1) & 1][j] = h;
      out[(size_t)rp * 512 + dir * 256 + j] = h;
    }
    __syncthreads();
  }
  for (int t = len; t < T_; ++t)
    if (gt == 0) out[(size_t)(t * B_ + b) * 512 + dir * 256 + j] = 0.f;
}

// ---------------- Viterbi (one wave per batch; ref fp-op order) ----------------
__global__ __launch_bounds__(64) void viterbi(
    const float* __restrict__ emis, const float* __restrict__ trans,
    const float* __restrict__ startv, const float* __restrict__ endv,
    const int* __restrict__ lens, int* __restrict__ outp) {
  int b = blockIdx.x, lane = threadIdx.x;
  __shared__ float tr[KTAG * KTAG];
  __shared__ float fin[KTAG];
  __shared__ unsigned char hist[T_ * KTAG];
  for (int i = lane; i < KTAG * KTAG; i += 64) tr[i] = trans[i];
  int len = lens[b];
  float score = (lane < KTAG) ? startv[lane] + emis[(size_t)b * 64 + lane] : -3e38f;
  __syncthreads();
  for (int t = 1; t < len; ++t) {
    float e = (lane < KTAG) ? emis[(size_t)(t * B_ + b) * 64 + lane] : 0.f;
    float best = -3e38f; int bp = 0;
    for (int p = 0; p < KTAG; ++p) {         // ascending p + strict '>': first-index
      float cand = (__shfl(score, p) + tr[p * KTAG + lane]) + e;  // ref op order
      if (cand > best) { best = cand; bp = p; }
    }
    if (lane < KTAG) { score = best; hist[t * KTAG + lane] = (unsigned char)bp; }
  }
  if (lane < KTAG) fin[lane] = score + endv[lane];
  __syncthreads();
  if (lane == 0) {
    float bb = -3e38f; int tag = 0;
    for (int p = 0; p < KTAG; ++p)
      if (fin[p] > bb) { bb = fin[p]; tag = p; }
    for (int t = len - 1; t >= 1; --t) {
      outp[t * B_ + b] = tag;
      tag = hist[t * KTAG + tag];
    }
    outp[b] = tag;
  }
  for (int t = len + lane; t < T_; t += 64) outp[t * B_ + b] = 0;
}

// ---------------- diagnostics (slim) ----------------
__global__ void sentinel_fill(int* __restrict__ outp, int val) {
  int i = blockIdx.x * 256 + threadIdx.x;
  if (i < TB_) outp[i] = val;
}
__global__ void diag_init(int* __restrict__ f) { if (threadIdx.x == 0) f[0] = 0; }
__global__ void check_nan(const float* __restrict__ p, long n, int* __restrict__ f) {
  long i0 = (long)blockIdx.x * 256 + threadIdx.x;
  int bad = 0;
  for (long i = i0; i < n; i += (long)gridDim.x * 256)
    if (!(fabsf(p[i]) <= 1e8f)) bad = 1;
  if (bad) atomicOr(&f[0], 1);
}
__global__ void verdict(const int* __restrict__ f, int* __restrict__ outp) {
  if (f[0]) outp[threadIdx.x] = -4096;
}

// ---------------- host ----------------

extern "C" void kernel_launch(void* const* d_in, const int* in_sizes, int n_in,
                              void* d_out, int out_size, void* d_ws, size_t ws_size,
                              hipStream_t stream) {
  int* outp = (int*)d_out;

  static const int exp_sizes[14] = {16384, 64, 15000000, 614400, 524288, 2048,
                                    1048576, 524288, 2048, 10240, 20, 400, 20, 20};
  int badi = (n_in == 14) ? -1 : 14;
  if (badi < 0)
    for (int i = 0; i < 14; ++i)
      if (in_sizes[i] != exp_sizes[i]) { badi = i; break; }
  if (badi >= 0) {
    hipLaunchKernelGGL(sentinel_fill, dim3((TB_ + 255) / 256), dim3(256), 0, stream,
                       outp, -(20000 + badi));
    return;
  }

  const int*   x      = (const int*)d_in[0];
  const int*   lens   = (const int*)d_in[1];
  const float* emb    = (const float*)d_in[2];
  const float* Wih0   = (const float*)d_in[3];
  const float* Whh0   = (const float*)d_in[4];
  const float* b0     = (const float*)d_in[5];
  const float* Wih1   = (const float*)d_in[6];
  const float* Whh1   = (const float*)d_in[7];
  const float* b1     = (const float*)d_in[8];
  const float* Wout   = (const float*)d_in[9];
  const float* bout   = (const float*)d_in[10];
  const float* trans  = (const float*)d_in[11];
  const float* startv = (const float*)d_in[12];
  const float* endv   = (const float*)d_in[13];

  // cascade: hi3b -> hi2 -> lo, gated on proof of residency (no scratch).
  static int chosen = -1;
  if (chosen < 0) {
    chosen = 0;
    hipFuncAttributes fa;
    if (hipFuncGetAttributes(&fa, reinterpret_cast<const void*>(&lstm_rec_hi2)) ==
            hipSuccess &&
        fa.localSizeBytes == 0 && fa.numRegs >= 150)
      chosen = 1;
    if (hipFuncGetAttributes(&fa, reinterpret_cast<const void*>(&lstm_rec_hi3b)) ==
            hipSuccess &&
        fa.localSizeBytes == 0 && fa.numRegs >= 150)
      chosen = 2;
  }

  const size_t sz_whh = (size_t)524288 * 4;   // 2 MiB per layer per layout

  const size_t need =
      (size_t)TB_ * 2048 * 4      // xg
    + (size_t)TB_ * EPAD * 4     // xsA
    + (size_t)TB_ * 512 * 4      // outh
    + (size_t)2048 * EPAD * 4    // B0t
    + (size_t)64 * 512 * 4       // Bot
    + 4 * sz_whh                 // whh{0,1} x {U,L}
    + 64 * 4                     // biaso
    + (size_t)TB_ * 64 * 4       // emis
    + 64;                        // diag

  if (ws_size < need) {
    hipLaunchKernelGGL(sentinel_fill, dim3((TB_ + 255) / 256), dim3(256), 0, stream,
                       outp, -(int)(10000 + (ws_size >> 20)));
    return;
  }

  char* w = (char*)d_ws;
  float* xg    = (float*)w;  w += (size_t)TB_ * 2048 * 4;
  float* xsA   = (float*)w;  w += (size_t)TB_ * EPAD * 4;
  float* outh  = (float*)w;  w += (size_t)TB_ * 512 * 4;
  float* B0t   = (float*)w;  w += (size_t)2048 * EPAD * 4;
  float* Bot   = (float*)w;  w += (size_t)64 * 512 * 4;
  float* whh0U = (float*)w;  w += sz_whh;
  float* whh1U = (float*)w;  w += sz_whh;
  float* whh0L = (float*)w;  w += sz_whh;
  float* whh1L = (float*)w;  w += sz_whh;
  float* biaso = (float*)w;  w += 64 * 4;
  float* emis  = (float*)w;  w += (size_t)TB_ * 64 * 4;
  int*   diag  = (int*)w;    w += 64;

  hipLaunchKernelGGL(diag_init, dim3(1), dim3(64), 0, stream, diag);
  hipLaunchKernelGGL(prep_embed, dim3(TB_), dim3(64), 0, stream, x, emb, xsA);
  hipLaunchKernelGGL(prep_b0t, dim3((2048 * EPAD + 255) / 256), dim3(256), 0, stream, Wih0, B0t);
  hipLaunchKernelGGL(prep_bot64, dim3(128), dim3(256), 0, stream, Wout, Bot, bout, biaso);
  if (chosen >= 1) {
    hipLaunchKernelGGL(prep_whh4, dim3(2048), dim3(256), 0, stream, Whh0, whh0U);
    hipLaunchKernelGGL(prep_whh4, dim3(2048), dim3(256), 0, stream, Whh1, whh1U);
  } else {
    hipLaunchKernelGGL(prep_whh2, dim3(2048), dim3(256), 0, stream, Whh0, whh0L);
    hipLaunchKernelGGL(prep_whh2, dim3(2048), dim3(256), 0, stream, Whh1, whh1L);
  }

  // layer 0
  hipLaunchKernelGGL(gemm_f32, dim3(256 * 32), dim3(256), 0, stream,
                     xsA, EPAD, B0t, EPAD, xg, 2048, b0, 32, EPAD);
  if (chosen == 2)
    hipLaunchKernelGGL(lstm_rec_hi3b, dim3(128), dim3(512), 0, stream, xg, whh0U, outh, lens);
  else if (chosen == 1)
    hipLaunchKernelGGL(lstm_rec_hi2, dim3(128), dim3(512), 0, stream, xg, whh0U, outh, lens);
  else
    hipLaunchKernelGGL(lstm_rec_lo, dim3(128), dim3(1024), 0, stream, xg, whh0L, outh, lens);
  // layer 1 (Wih1/b1 used directly: [2048][512] row-major, K=512)
  hipLaunchKernelGGL(gemm_f32, dim3(256 * 32), dim3(256), 0, stream,
                     outh, 512, Wih1, 512, xg, 2048, b1, 32, 512);
  if (chosen == 2)
    hipLaunchKernelGGL(lstm_rec_hi3b, dim3(128), dim3(512), 0, stream, xg, whh1U, outh, lens);
  else if (chosen == 1)
    hipLaunchKernelGGL(lstm_rec_hi2, dim3(128), dim3(512), 0, stream, xg, whh1U, outh, lens);
  else
    hipLaunchKernelGGL(lstm_rec_lo, dim3(128), dim3(1024), 0, stream, xg, whh1L, outh, lens);
  // emissions (N padded to 64) + decode
  hipLaunchKernelGGL(gemm_f32, dim3(256), dim3(256), 0, stream,
                     outh, 512, Bot, 512, emis, 64, biaso, 1, 512);
  hipLaunchKernelGGL(check_nan, dim3(256), dim3(256), 0, stream,
                     emis, (long)TB_ * 64, diag);
  hipLaunchKernelGGL(viterbi, dim3(B_), dim3(64), 0, stream,
                     emis, trans, startv, endv, lens, outp);
  hipLaunchKernelGGL(verdict, dim3(1), dim3(64), 0, stream, diag, outp);
}

// Round 10
// 3983.939 us; speedup vs baseline: 1.1958x; 1.0043x over previous
//
#include <hip/hip_runtime.h>
#include <stdint.h>

// BiLSTM-CRF on gfx950 — fp32 (validated absmax 0.0). R16: cascade
// hi5 -> hi2 -> lo. hi5 = R10's 1024-thr kernel (KR=72 pinned, KL=36 LDS,
// 148k streamed = 606 KB/step) which failed ONLY because __launch_bounds__
// overrode waves_per_eu -> 64-reg heuristic -> spill. R12/R13 proved the fix:
// amdgpu_flat_work_group_size + amdgpu_waves_per_eu WITHOUT launch_bounds
// gives an honest budget (512/4 = 128 regs). 16-wave TLP reaches ~135 GB/s/CU
// (R6/R8) vs hi2's 8-wave 92 GB/s -> ~4.7 us/step vs 6.14.
// hi2 = R13 verbatim (1551-1571 us proven). lo = R8 verbatim (1963 us proven).

#define T_ 256
#define B_ 64
#define EPAD 304
#define KTAG 20
#define TB_ (T_ * B_)

// hi2 partition (global k-quads 0..63, q ascending)
#define QR2 22                  // quads resident per gate-row (176 pinned, proven)
#define QL2A 8                  // quads in LDS (128 KiB)
#define QS2A 34                 // streamed

// hi5 partition (per gate-row of 256 k; R10 layout, proven numerics)
#define KR5 72                  // k resident in VGPR/AGPR (pinned)
#define KLQ5 9                  // float4-quads in LDS (144 KiB)
#define NQS5 37                 // streamed float4 quads (148 k)
#define WLDS_OFF5 (2 * KR5 * 1024)                   // 147456 floats
#define WSTR_OFF5 (WLDS_OFF5 + 2 * KLQ5 * 1024 * 4)  // 221184 floats

// lo (R8) partition
#define KR_LO 64
#define KLQ_LO 3
#define NQS_LO 45
#define WLDS_OFF_LO (2 * KR_LO * 1024)                    // 131072 floats
#define WSTR_OFF_LO (WLDS_OFF_LO + 2 * KLQ_LO * 1024 * 4) // 155648 floats

__device__ __forceinline__ float rlane(float v, int l) {
  return __int_as_float(__builtin_amdgcn_readlane(__float_as_int(v), l));
}

// ---------------- prep ----------------

__global__ void prep_embed(const int* __restrict__ x, const float* __restrict__ emb,
                           float* __restrict__ xsA) {
  int r = blockIdx.x;
  int tok = x[r];
  const float* src = emb + (size_t)tok * 300;
  for (int e = threadIdx.x; e < EPAD; e += 64)
    xsA[(size_t)r * EPAD + e] = (e < 300) ? src[e] : 0.f;
}

__global__ void prep_b0t(const float* __restrict__ Wih0, float* __restrict__ B0t) {
  int idx = blockIdx.x * 256 + threadIdx.x;
  if (idx >= 2048 * EPAD) return;
  int n = idx / EPAD, k = idx % EPAD;
  B0t[idx] = (k < 300) ? Wih0[(size_t)n * 300 + k] : 0.f;
}

__global__ void prep_bot64(const float* __restrict__ Wout, float* __restrict__ Bot,
                           const float* __restrict__ bout, float* __restrict__ biaso) {
  int idx = blockIdx.x * 256 + threadIdx.x;   // 64*512
  int n = idx >> 9, k = idx & 511;
  Bot[idx] = (n < KTAG) ? Wout[(size_t)n * 512 + k] : 0.f;
  if (idx < 64) biaso[idx] = (idx < KTAG) ? bout[idx] : 0.f;
}

// hi2 layout: whhU[d][q=k/4][gate][j][e]
__global__ void prep_whh4(const float* __restrict__ Whh, float* __restrict__ whhU) {
  int idx = blockIdx.x * 256 + threadIdx.x;   // 524288
  int d = idx >> 18, rem = idx & 262143, row = rem >> 8, k = rem & 255;
  float v = Whh[(size_t)d * 262144 + (size_t)row * 256 + k];
  int gt = row >> 8, j = row & 255;
  int q = k >> 2, e = k & 3;
  whhU[((((size_t)d * 64 + q) * 4 + gt) * 256 + j) * 4 + e] = v;
}

// hi5 layout (R10's): thread tg owns row (tg&3)*256 + (tg>>2).
// resident [d][k<KR5][tg]; LDS [d][q][tg][4]; streamed [d][q][tg][4].
__global__ void prep_whh5(const float* __restrict__ Whh, float* __restrict__ whhV) {
  int idx = blockIdx.x * 256 + threadIdx.x;   // 524288
  int d = idx >> 18, rem = idx & 262143, k = rem >> 10, tg = rem & 1023;
  int row = (tg & 3) * 256 + (tg >> 2);
  float v = Whh[(size_t)d * 262144 + (size_t)row * 256 + k];
  if (k < KR5) {
    whhV[(size_t)(d * KR5 + k) * 1024 + tg] = v;
  } else if (k < KR5 + 4 * KLQ5) {
    int kk = k - KR5, q = kk >> 2, e = kk & 3;
    whhV[WLDS_OFF5 + (size_t)((d * KLQ5 + q) * 1024 + tg) * 4 + e] = v;
  } else {
    int kk = k - KR5 - 4 * KLQ5, q = kk >> 2, e = kk & 3;
    whhV[WSTR_OFF5 + (size_t)((d * NQS5 + q) * 1024 + tg) * 4 + e] = v;
  }
}

// lo layout (R8)
__global__ void prep_whh2(const float* __restrict__ Whh, float* __restrict__ whhL) {
  int idx = blockIdx.x * 256 + threadIdx.x;   // 524288
  int d = idx >> 18, rem = idx & 262143, k = rem >> 10, tg = rem & 1023;
  int row = (tg & 3) * 256 + (tg >> 2);
  float v = Whh[(size_t)d * 262144 + (size_t)row * 256 + k];
  if (k < KR_LO) {
    whhL[(size_t)(d * KR_LO + k) * 1024 + tg] = v;
  } else if (k < KR_LO + 12) {
    int kk = k - KR_LO, q = kk >> 2, e = kk & 3;
    whhL[WLDS_OFF_LO + (size_t)((d * KLQ_LO + q) * 1024 + tg) * 4 + e] = v;
  } else {
    int kk = k - KR_LO - 12, q = kk >> 2, e = kk & 3;
    whhL[WSTR_OFF_LO + (size_t)((d * NQS_LO + q) * 1024 + tg) * 4 + e] = v;
  }
}

// ---------------- fp32 GEMM: C[M,N] = A[M,K] * Bt[N,K]^T + bias ----------------
__global__ __launch_bounds__(256) void gemm_f32(
    const float* __restrict__ A, int lda, const float* __restrict__ Bt, int ldb,
    float* __restrict__ C, int ldc, const float* __restrict__ bias,
    int ntn, int K) {
  const int tm = blockIdx.x / ntn, tn = blockIdx.x % ntn;
  const int m0 = tm * 64, n0 = tn * 64;
  __shared__ __align__(16) float As[16][64];
  __shared__ __align__(16) float Bs[16][64];
  const int tid = threadIdx.x;
  const int mm = tid >> 2, kq = (tid & 3) * 4;
  const int tx = tid & 15, ty = tid >> 4;
  float acc[4][4] = {};
  for (int k0 = 0; k0 < K; k0 += 16) {
    float4 av = *(const float4*)&A[(size_t)(m0 + mm) * lda + k0 + kq];
    float4 bv = *(const float4*)&Bt[(size_t)(n0 + mm) * ldb + k0 + kq];
    __syncthreads();                       // guard prev-iter LDS reads
    As[kq + 0][mm] = av.x; As[kq + 1][mm] = av.y;
    As[kq + 2][mm] = av.z; As[kq + 3][mm] = av.w;
    Bs[kq + 0][mm] = bv.x; Bs[kq + 1][mm] = bv.y;
    Bs[kq + 2][mm] = bv.z; Bs[kq + 3][mm] = bv.w;
    __syncthreads();
#pragma unroll
    for (int kk = 0; kk < 16; ++kk) {
      float4 a4 = *(const float4*)&As[kk][ty * 4];
      float4 b4 = *(const float4*)&Bs[kk][tx * 4];
      acc[0][0] += a4.x * b4.x; acc[0][1] += a4.x * b4.y;
      acc[0][2] += a4.x * b4.z; acc[0][3] += a4.x * b4.w;
      acc[1][0] += a4.y * b4.x; acc[1][1] += a4.y * b4.y;
      acc[1][2] += a4.y * b4.z; acc[1][3] += a4.y * b4.w;
      acc[2][0] += a4.z * b4.x; acc[2][1] += a4.z * b4.y;
      acc[2][2] += a4.z * b4.z; acc[2][3] += a4.z * b4.w;
      acc[3][0] += a4.w * b4.x; acc[3][1] += a4.w * b4.y;
      acc[3][2] += a4.w * b4.z; acc[3][3] += a4.w * b4.w;
    }
  }
#pragma unroll
  for (int i = 0; i < 4; ++i)
#pragma unroll
    for (int j = 0; j < 4; ++j)
      C[(size_t)(m0 + ty * 4 + i) * ldc + n0 + tx * 4 + j] =
          acc[i][j] + bias[n0 + tx * 4 + j];
}

// ---------------- hi5 LSTM: R10 body + R13 attribute mechanism ----------
// 1024 thr (16 waves -> TLP for ~135 GB/s/CU), flat_work_group_size +
// waves_per_eu(4,4) and NO launch_bounds -> honest 128-reg budget so the
// KR5=72 pins hold. Thread tg owns gate row (tg&3)*256 + (tg>>2). rlane
// h-broadcast, shfl gate gather, one barrier/step.
__global__ __attribute__((amdgpu_flat_work_group_size(1024, 1024),
                          amdgpu_waves_per_eu(4, 4)))
void lstm_rec_hi5(const float* __restrict__ xg, const float* __restrict__ whhV,
                  float* __restrict__ out, const int* __restrict__ lens) {
  const int wg = blockIdx.x, dir = wg & 1, b = wg >> 1;
  const int len = lens[b];
  const int tg = threadIdx.x;
  const int j = tg >> 2, gt = tg & 3;
  const int row = gt * 256 + j;

  float wres[KR5];
#pragma unroll
  for (int k = 0; k < KR5; ++k)
    wres[k] = whhV[(size_t)(dir * KR5 + k) * 1024 + tg];
#pragma unroll
  for (int k = 0; k < KR5; ++k)
    asm volatile("" : "+v"(wres[k]));

  __shared__ __align__(16) float4 wlds[KLQ5][1024];   // 144 KiB
  __shared__ __align__(16) float hsd[2][256];
#pragma unroll
  for (int q = 0; q < KLQ5; ++q)
    wlds[q][tg] = *(const float4*)&whhV[WLDS_OFF5 + (size_t)((dir * KLQ5 + q) * 1024 + tg) * 4];
  if (tg < 256) hsd[0][tg] = 0.f;
  float c = 0.f;
  __syncthreads();

  const float* sp = whhV + WSTR_OFF5 + (size_t)dir * NQS5 * 4096 + (size_t)tg * 4;
  const int lane = tg & 63, qb = lane & ~3;

  for (int s = 0; s < len; ++s) {
    const int t = dir ? (len - 1 - s) : s;   // bwd consumes & writes reversed pos
    const int rp = t * B_ + b;
    float xv = xg[(size_t)rp * 2048 + dir * 1024 + row];
    float4 hv = *(const float4*)&hsd[s & 1][lane * 4];  // lane l: h[4l..4l+3]

    float acc0 = 0.f, acc1 = 0.f;
#pragma unroll
    for (int q = 0; q < KR5 / 4; ++q) {      // k ascending = validated FP chain
      float b0 = rlane(hv.x, q), b1 = rlane(hv.y, q);
      float b2 = rlane(hv.z, q), b3 = rlane(hv.w, q);
      acc0 += wres[4 * q + 0] * b0 + wres[4 * q + 1] * b1;
      acc1 += wres[4 * q + 2] * b2 + wres[4 * q + 3] * b3;
    }
#pragma unroll
    for (int q3 = 0; q3 < KLQ5; ++q3) {
      int q = KR5 / 4 + q3;
      float4 wl = wlds[q3][tg];
      float b0 = rlane(hv.x, q), b1 = rlane(hv.y, q);
      float b2 = rlane(hv.z, q), b3 = rlane(hv.w, q);
      acc0 += wl.x * b0 + wl.y * b1;
      acc1 += wl.z * b2 + wl.w * b3;
    }
#pragma unroll 5
    for (int qq = 0; qq < NQS5; ++qq) {
      int q = KR5 / 4 + KLQ5 + qq;
      float4 wv = *(const float4*)(sp + (size_t)qq * 4096);
      float b0 = rlane(hv.x, q), b1 = rlane(hv.y, q);
      float b2 = rlane(hv.z, q), b3 = rlane(hv.w, q);
      acc0 += wv.x * b0 + wv.y * b1;
      acc1 += wv.z * b2 + wv.w * b3;
    }

    float a = acc0 + acc1 + xv;
    float v1 = __shfl(a, qb | 1);
    float v2 = __shfl(a, qb | 2);
    float v3 = __shfl(a, qb | 3);
    if (gt == 0) {
      float si = 1.f / (1.f + expf(-a));     // i
      float sf = 1.f / (1.f + expf(-v1));    // f
      float so = 1.f / (1.f + expf(-v3));    // o
      c = sf * c + si * tanhf(v2);           // g = v2
      float h = so * tanhf(c);
      hsd[(s + 1) & 1][j] = h;
      out[(size_t)rp * 512 + dir * 256 + j] = h;
    }
    __syncthreads();                          // one barrier per step
  }
  for (int t = len; t < T_; ++t)              // pack_padded: padded outputs zero
    if (gt == 0) out[(size_t)(t * B_ + b) * 512 + dir * 256 + j] = 0.f;
}

// ---------------- hi2 LSTM: R13 verbatim (proven 1551-1571 us) ----------
__global__ __attribute__((amdgpu_flat_work_group_size(512, 512),
                          amdgpu_waves_per_eu(2, 2)))
void lstm_rec_hi2(const float* __restrict__ xg, const float* __restrict__ whhU,
                  float* __restrict__ out, const int* __restrict__ lens) {
  const int wg = blockIdx.x, d = wg & 1, b = wg >> 1;
  const int len = lens[b];
  const int tg = threadIdx.x;
  const int j = tg & 255, gp = tg >> 8;    // gp 0: gates i,f ; gp 1: gates g,o
  const int g0 = gp * 2;
  const int l = tg & 63;
  const float* wb = whhU + (size_t)d * 64 * 4096;

  float4 wA[QR2], wB[QR2];
#pragma unroll
  for (int q = 0; q < QR2; ++q) {
    wA[q] = *(const float4*)(wb + ((size_t)(q * 4 + g0) * 256 + j) * 4);
    wB[q] = *(const float4*)(wb + ((size_t)(q * 4 + g0 + 1) * 256 + j) * 4);
  }
#pragma unroll
  for (int q = 0; q < QR2; ++q) {
    asm volatile("" : "+v"(wA[q].x), "+v"(wA[q].y), "+v"(wA[q].z), "+v"(wA[q].w));
    asm volatile("" : "+v"(wB[q].x), "+v"(wB[q].y), "+v"(wB[q].z), "+v"(wB[q].w));
  }

  __shared__ __align__(16) float4 wlds[QL2A][4][256];  // 128 KiB
  __shared__ __align__(16) float hsd[2][256];
  __shared__ __align__(8) float2 exch[256];
  for (int i = tg; i < QL2A * 4 * 256; i += 512) {
    int q3 = i >> 10, g = (i >> 8) & 3, jj = i & 255;
    wlds[q3][g][jj] =
        *(const float4*)(wb + ((size_t)((QR2 + q3) * 4 + g) * 256 + jj) * 4);
  }
  if (tg < 256) hsd[0][tg] = 0.f;
  float c = 0.f;
  __syncthreads();

  for (int s = 0; s < len; ++s) {
    const int t = d ? (len - 1 - s) : s;
    const int rp = t * B_ + b;
    const size_t xb = (size_t)rp * 2048 + d * 1024 + (size_t)g0 * 256 + j;
    float xv0 = xg[xb];
    float xv1 = xg[xb + 256];
    float4 hv = *(const float4*)&hsd[s & 1][l * 4];

    float aA0 = 0.f, aA1 = 0.f, aB0 = 0.f, aB1 = 0.f;
#pragma unroll
    for (int q = 0; q < QR2; ++q) {
      float b0 = rlane(hv.x, q), b1 = rlane(hv.y, q);
      float b2 = rlane(hv.z, q), b3 = rlane(hv.w, q);
      aA0 += wA[q].x * b0 + wA[q].y * b1;  aA1 += wA[q].z * b2 + wA[q].w * b3;
      aB0 += wB[q].x * b0 + wB[q].y * b1;  aB1 += wB[q].z * b2 + wB[q].w * b3;
    }
#pragma unroll
    for (int q3 = 0; q3 < QL2A; ++q3) {
      int q = QR2 + q3;
      float b0 = rlane(hv.x, q), b1 = rlane(hv.y, q);
      float b2 = rlane(hv.z, q), b3 = rlane(hv.w, q);
      float4 wa = wlds[q3][g0][j], wbq = wlds[q3][g0 + 1][j];
      aA0 += wa.x * b0 + wa.y * b1;   aA1 += wa.z * b2 + wa.w * b3;
      aB0 += wbq.x * b0 + wbq.y * b1; aB1 += wbq.z * b2 + wbq.w * b3;
    }
#pragma unroll 2
    for (int qs = 0; qs < QS2A; ++qs) {
      int q = QR2 + QL2A + qs;
      float4 wa = *(const float4*)(wb + ((size_t)(q * 4 + g0) * 256 + j) * 4);
      float4 wbq = *(const float4*)(wb + ((size_t)(q * 4 + g0 + 1) * 256 + j) * 4);
      float b0 = rlane(hv.x, q), b1 = rlane(hv.y, q);
      float b2 = rlane(hv.z, q), b3 = rlane(hv.w, q);
      aA0 += wa.x * b0 + wa.y * b1;   aA1 += wa.z * b2 + wa.w * b3;
      aB0 += wbq.x * b0 + wbq.y * b1; aB1 += wbq.z * b2 + wbq.w * b3;
    }

    float aA = aA0 + aA1 + xv0;
    float aB = aB0 + aB1 + xv1;
    if (gp == 1) exch[j] = make_float2(aA, aB);
    __syncthreads();
    if (gp == 0) {
      float2 go = exch[j];
      float si = 1.f / (1.f + expf(-aA));
      float sf = 1.f / (1.f + expf(-aB));
      float so = 1.f / (1.f + expf(-go.y));
      c = sf * c + si * tanhf(go.x);
      float h = so * tanhf(c);
      hsd[(s + 1) & 1][j] = h;
      out[(size_t)rp * 512 + d * 256 + j] = h;
    }
    __syncthreads();
  }
  if (gp == 0)
    for (int t = len; t < T_; ++t)
      out[(size_t)(t * B_ + b) * 512 + d * 256 + j] = 0.f;
}

// ---------------- lo LSTM: verbatim R8 (proven 1963 us, absmax 0.0) ----------
__global__ __launch_bounds__(1024, 4) void lstm_rec_lo(
    const float* __restrict__ xg, const float* __restrict__ whhL,
    float* __restrict__ out, const int* __restrict__ lens) {
  const int wg = blockIdx.x, dir = wg & 1, b = wg >> 1;
  const int len = lens[b];
  const int tg = threadIdx.x;
  const int j = tg >> 2, gt = tg & 3;
  const int row = gt * 256 + j;

  float wres[KR_LO];
#pragma unroll
  for (int k = 0; k < KR_LO; ++k)
    wres[k] = whhL[(size_t)(dir * KR_LO + k) * 1024 + tg];

  __shared__ __align__(16) float4 wlds[KLQ_LO][1024];
  __shared__ __align__(16) float hsd[2][256];
#pragma unroll
  for (int q = 0; q < KLQ_LO; ++q)
    wlds[q][tg] = *(const float4*)&whhL[WLDS_OFF_LO + (size_t)((dir * KLQ_LO + q) * 1024 + tg) * 4];
  if (tg < 256) hsd[0][tg] = 0.f;
  float c = 0.f;
  __syncthreads();

  const float* sp = whhL + WSTR_OFF_LO + (size_t)dir * NQS_LO * 4096 + (size_t)tg * 4;
  const int lane = tg & 63, qb = lane & ~3;

  for (int s = 0; s < len; ++s) {
    const int t = dir ? (len - 1 - s) : s;
    const int rp = t * B_ + b;
    float xv = xg[(size_t)rp * 2048 + dir * 1024 + row];
    float4 hv = *(const float4*)&hsd[s & 1][lane * 4];

    float acc0 = 0.f, acc1 = 0.f;
#pragma unroll
    for (int q = 0; q < KR_LO / 4; ++q) {
      float b0 = rlane(hv.x, q), b1 = rlane(hv.y, q);
      float b2 = rlane(hv.z, q), b3 = rlane(hv.w, q);
      acc0 += wres[4 * q + 0] * b0 + wres[4 * q + 1] * b1;
      acc1 += wres[4 * q + 2] * b2 + wres[4 * q + 3] * b3;
    }
#pragma unroll
    for (int q3 = 0; q3 < KLQ_LO; ++q3) {
      int q = KR_LO / 4 + q3;
      float4 wl = wlds[q3][tg];
      float b0 = rlane(hv.x, q), b1 = rlane(hv.y, q);
      float b2 = rlane(hv.z, q), b3 = rlane(hv.w, q);
      acc0 += wl.x * b0 + wl.y * b1;
      acc1 += wl.z * b2 + wl.w * b3;
    }
#pragma unroll 5
    for (int qq = 0; qq < NQS_LO; ++qq) {
      int q = KR_LO / 4 + KLQ_LO + qq;
      float4 wv = *(const float4*)(sp + (size_t)qq * 4096);
      float b0 = rlane(hv.x, q), b1 = rlane(hv.y, q);
      float b2 = rlane(hv.z, q), b3 = rlane(hv.w, q);
      acc0 += wv.x * b0 + wv.y * b1;
      acc1 += wv.z * b2 + wv.w * b3;
    }

    float a = acc0 + acc1 + xv;
    float v1 = __shfl(a, qb | 1);
    float v2 = __shfl(a, qb | 2);
    float v3 = __shfl(a, qb | 3);
    if (gt == 0) {
      float si = 1.f / (1.f + expf(-a));
      float sf = 1.f / (1.f + expf(-v1));
      float so = 1.f / (1.f + expf(-v3));
      c = sf * c + si * tanhf(v2);
      float h = so * tanhf(c);
      hsd[(s + 1) & 1][j] = h;
      out[(size_t)rp * 512 + dir * 256 + j] = h;
    }
    __syncthreads();
  }
  for (int t = len; t < T_; ++t)
    if (gt == 0) out[(size_t)(t * B_ + b) * 512 + dir * 256 + j] = 0.f;
}

// ---------------- Viterbi (one wave per batch; ref fp-op order) ----------------
__global__ __launch_bounds__(64) void viterbi(
    const float* __restrict__ emis, const float* __restrict__ trans,
    const float* __restrict__ startv, const float* __restrict__ endv,
    const int* __restrict__ lens, int* __restrict__ outp) {
  int b = blockIdx.x, lane = threadIdx.x;
  __shared__ float tr[KTAG * KTAG];
  __shared__ float fin[KTAG];
  __shared__ unsigned char hist[T_ * KTAG];
  for (int i = lane; i < KTAG * KTAG; i += 64) tr[i] = trans[i];
  int len = lens[b];
  float score = (lane < KTAG) ? startv[lane] + emis[(size_t)b * 64 + lane] : -3e38f;
  __syncthreads();
  for (int t = 1; t < len; ++t) {
    float e = (lane < KTAG) ? emis[(size_t)(t * B_ + b) * 64 + lane] : 0.f;
    float best = -3e38f; int bp = 0;
    for (int p = 0; p < KTAG; ++p) {         // ascending p + strict '>': first-index
      float cand = (__shfl(score, p) + tr[p * KTAG + lane]) + e;  // ref op order
      if (cand > best) { best = cand; bp = p; }
    }
    if (lane < KTAG) { score = best; hist[t * KTAG + lane] = (unsigned char)bp; }
  }
  if (lane < KTAG) fin[lane] = score + endv[lane];
  __syncthreads();
  if (lane == 0) {
    float bb = -3e38f; int tag = 0;
    for (int p = 0; p < KTAG; ++p)
      if (fin[p] > bb) { bb = fin[p]; tag = p; }
    for (int t = len - 1; t >= 1; --t) {
      outp[t * B_ + b] = tag;
      tag = hist[t * KTAG + tag];
    }
    outp[b] = tag;
  }
  for (int t = len + lane; t < T_; t += 64) outp[t * B_ + b] = 0;
}

// ---------------- diagnostics (slim) ----------------
__global__ void sentinel_fill(int* __restrict__ outp, int val) {
  int i = blockIdx.x * 256 + threadIdx.x;
  if (i < TB_) outp[i] = val;
}
__global__ void diag_init(int* __restrict__ f) { if (threadIdx.x == 0) f[0] = 0; }
__global__ void check_nan(const float* __restrict__ p, long n, int* __restrict__ f) {
  long i0 = (long)blockIdx.x * 256 + threadIdx.x;
  int bad = 0;
  for (long i = i0; i < n; i += (long)gridDim.x * 256)
    if (!(fabsf(p[i]) <= 1e8f)) bad = 1;
  if (bad) atomicOr(&f[0], 1);
}
__global__ void verdict(const int* __restrict__ f, int* __restrict__ outp) {
  if (f[0]) outp[threadIdx.x] = -4096;
}

// ---------------- host ----------------

extern "C" void kernel_launch(void* const* d_in, const int* in_sizes, int n_in,
                              void* d_out, int out_size, void* d_ws, size_t ws_size,
                              hipStream_t stream) {
  int* outp = (int*)d_out;

  static const int exp_sizes[14] = {16384, 64, 15000000, 614400, 524288, 2048,
                                    1048576, 524288, 2048, 10240, 20, 400, 20, 20};
  int badi = (n_in == 14) ? -1 : 14;
  if (badi < 0)
    for (int i = 0; i < 14; ++i)
      if (in_sizes[i] != exp_sizes[i]) { badi = i; break; }
  if (badi >= 0) {
    hipLaunchKernelGGL(sentinel_fill, dim3((TB_ + 255) / 256), dim3(256), 0, stream,
                       outp, -(20000 + badi));
    return;
  }

  const int*   x      = (const int*)d_in[0];
  const int*   lens   = (const int*)d_in[1];
  const float* emb    = (const float*)d_in[2];
  const float* Wih0   = (const float*)d_in[3];
  const float* Whh0   = (const float*)d_in[4];
  const float* b0     = (const float*)d_in[5];
  const float* Wih1   = (const float*)d_in[6];
  const float* Whh1   = (const float*)d_in[7];
  const float* b1     = (const float*)d_in[8];
  const float* Wout   = (const float*)d_in[9];
  const float* bout   = (const float*)d_in[10];
  const float* trans  = (const float*)d_in[11];
  const float* startv = (const float*)d_in[12];
  const float* endv   = (const float*)d_in[13];

  // cascade: hi5 -> hi2 -> lo, gated on proof of residency (no scratch).
  static int chosen = -1;
  if (chosen < 0) {
    chosen = 0;
    hipFuncAttributes fa;
    if (hipFuncGetAttributes(&fa, reinterpret_cast<const void*>(&lstm_rec_hi2)) ==
            hipSuccess &&
        fa.localSizeBytes == 0 && fa.numRegs >= 150)
      chosen = 1;
    if (hipFuncGetAttributes(&fa, reinterpret_cast<const void*>(&lstm_rec_hi5)) ==
            hipSuccess &&
        fa.localSizeBytes == 0 && fa.numRegs >= 100)
      chosen = 3;
  }

  const size_t sz_whh = (size_t)524288 * 4;   // 2 MiB per layer per layout

  const size_t need =
      (size_t)TB_ * 2048 * 4      // xg
    + (size_t)TB_ * EPAD * 4     // xsA
    + (size_t)TB_ * 512 * 4      // outh
    + (size_t)2048 * EPAD * 4    // B0t
    + (size_t)64 * 512 * 4       // Bot
    + 6 * sz_whh                 // whh{0,1} x {U,V,L}
    + 64 * 4                     // biaso
    + (size_t)TB_ * 64 * 4       // emis
    + 64;                        // diag

  if (ws_size < need) {
    hipLaunchKernelGGL(sentinel_fill, dim3((TB_ + 255) / 256), dim3(256), 0, stream,
                       outp, -(int)(10000 + (ws_size >> 20)));
    return;
  }

  char* w = (char*)d_ws;
  float* xg    = (float*)w;  w += (size_t)TB_ * 2048 * 4;
  float* xsA   = (float*)w;  w += (size_t)TB_ * EPAD * 4;
  float* outh  = (float*)w;  w += (size_t)TB_ * 512 * 4;
  float* B0t   = (float*)w;  w += (size_t)2048 * EPAD * 4;
  float* Bot   = (float*)w;  w += (size_t)64 * 512 * 4;
  float* whh0U = (float*)w;  w += sz_whh;
  float* whh1U = (float*)w;  w += sz_whh;
  float* whh0V = (float*)w;  w += sz_whh;
  float* whh1V = (float*)w;  w += sz_whh;
  float* whh0L = (float*)w;  w += sz_whh;
  float* whh1L = (float*)w;  w += sz_whh;
  float* biaso = (float*)w;  w += 64 * 4;
  float* emis  = (float*)w;  w += (size_t)TB_ * 64 * 4;
  int*   diag  = (int*)w;    w += 64;

  hipLaunchKernelGGL(diag_init, dim3(1), dim3(64), 0, stream, diag);
  hipLaunchKernelGGL(prep_embed, dim3(TB_), dim3(64), 0, stream, x, emb, xsA);
  hipLaunchKernelGGL(prep_b0t, dim3((2048 * EPAD + 255) / 256), dim3(256), 0, stream, Wih0, B0t);
  hipLaunchKernelGGL(prep_bot64, dim3(128), dim3(256), 0, stream, Wout, Bot, bout, biaso);
  if (chosen == 3) {
    hipLaunchKernelGGL(prep_whh5, dim3(2048), dim3(256), 0, stream, Whh0, whh0V);
    hipLaunchKernelGGL(prep_whh5, dim3(2048), dim3(256), 0, stream, Whh1, whh1V);
  } else if (chosen == 1) {
    hipLaunchKernelGGL(prep_whh4, dim3(2048), dim3(256), 0, stream, Whh0, whh0U);
    hipLaunchKernelGGL(prep_whh4, dim3(2048), dim3(256), 0, stream, Whh1, whh1U);
  } else {
    hipLaunchKernelGGL(prep_whh2, dim3(2048), dim3(256), 0, stream, Whh0, whh0L);
    hipLaunchKernelGGL(prep_whh2, dim3(2048), dim3(256), 0, stream, Whh1, whh1L);
  }

  // layer 0
  hipLaunchKernelGGL(gemm_f32, dim3(256 * 32), dim3(256), 0, stream,
                     xsA, EPAD, B0t, EPAD, xg, 2048, b0, 32, EPAD);
  if (chosen == 3)
    hipLaunchKernelGGL(lstm_rec_hi5, dim3(128), dim3(1024), 0, stream, xg, whh0V, outh, lens);
  else if (chosen == 1)
    hipLaunchKernelGGL(lstm_rec_hi2, dim3(128), dim3(512), 0, stream, xg, whh0U, outh, lens);
  else
    hipLaunchKernelGGL(lstm_rec_lo, dim3(128), dim3(1024), 0, stream, xg, whh0L, outh, lens);
  // layer 1 (Wih1/b1 used directly: [2048][512] row-major, K=512)
  hipLaunchKernelGGL(gemm_f32, dim3(256 * 32), dim3(256), 0, stream,
                     outh, 512, Wih1, 512, xg, 2048, b1, 32, 512);
  if (chosen == 3)
    hipLaunchKernelGGL(lstm_rec_hi5, dim3(128), dim3(1024), 0, stream, xg, whh1V, outh, lens);
  else if (chosen == 1)
    hipLaunchKernelGGL(lstm_rec_hi2, dim3(128), dim3(512), 0, stream, xg, whh1U, outh, lens);
  else
    hipLaunchKernelGGL(lstm_rec_lo, dim3(128), dim3(1024), 0, stream, xg, whh1L, outh, lens);
  // emissions (N padded to 64) + decode
  hipLaunchKernelGGL(gemm_f32, dim3(256), dim3(256), 0, stream,
                     outh, 512, Bot, 512, emis, 64, biaso, 1, 512);
  hipLaunchKernelGGL(check_nan, dim3(256), dim3(256), 0, stream,
                     emis, (long)TB_ * 64, diag);
  hipLaunchKernelGGL(viterbi, dim3(B_), dim3(64), 0, stream,
                     emis, trans, startv, endv, lens, outp);
  hipLaunchKernelGGL(verdict, dim3(1), dim3(64), 0, stream, diag, outp);
}